// Round 10
// baseline (750.414 us; speedup 1.0000x reference)
//
#include <hip/hip_runtime.h>
#include <math.h>

#define D_OPT   128
#define N_SIM   2048
#define M_STEPS 64
#define HID     64

// Round 16: R15 (737us) + update-phase instruction diet.
// Confirmed model (R8/R9b/R15): only issued-work cuts move this kernel;
// schedule levers (TLP/vmcnt/ladder-count/phase-mix/ILP-depth) all null.
// Changes vs R15 (update phase only):
//  - w3/b3 scaled by 2*log2e at staging -> L3 MFMA emits o' = 2*log2e*o;
//    tanh = 1 - 2*rcp(exp2(o')+1) with DIRECT v_exp_f32 (no muls); b3 rides
//    in the L3 C-splat again (R14-validated piece) -> -8 VALU/update.
//  - dt*(s+1) via running accumulator (-2 VALU).
// Pipeline (validated): L1 = mfma 16x16x16f16 (bias k-slot 3 x packed 1.0);
// L2 = 2x mfma 16x16x32 (baked k-permutation); L3 = 2x mfma 16x16x32, w3 row 0.

typedef _Float16 f16x8 __attribute__((ext_vector_type(8)));
typedef _Float16 f16x4 __attribute__((ext_vector_type(4)));
typedef _Float16 f16x2 __attribute__((ext_vector_type(2)));
typedef float    f32x4 __attribute__((ext_vector_type(4)));
typedef unsigned int u32;
typedef u32 u32x2 __attribute__((ext_vector_type(2)));
typedef u32 u32x4 __attribute__((ext_vector_type(4)));

#define KEXP 2.8853900817779268f   // 2 * log2(e)

__device__ __forceinline__ u32 pk2u(float a, float b) {
#if __has_builtin(__builtin_amdgcn_cvt_pkrtz)
    return __builtin_bit_cast(u32, __builtin_amdgcn_cvt_pkrtz(a, b));
#else
    f16x2 p; p[0] = (_Float16)a; p[1] = (_Float16)b;
    return __builtin_bit_cast(u32, p);
#endif
}

__device__ __forceinline__ u32 pk_relu_cvt(float a, float b) {
    f16x2 p = __builtin_bit_cast(f16x2, pk2u(a, b));
    const f16x2 z = { (_Float16)0.0f, (_Float16)0.0f };
#if __has_builtin(__builtin_elementwise_max)
    p = __builtin_elementwise_max(p, z);
#else
    p[0] = p[0] > z[0] ? p[0] : z[0];
    p[1] = p[1] > z[1] ? p[1] : z[1];
#endif
    return __builtin_bit_cast(u32, p);
}

__device__ __forceinline__ float fast_exp2(float x) {
#if __has_builtin(__builtin_amdgcn_exp2f)
    return __builtin_amdgcn_exp2f(x);
#else
    return __expf(x * 0.6931471805599453f);
#endif
}

// tanh from o' = 2*log2e*o:  1 - 2*rcp(exp2(o')+1)
__device__ __forceinline__ float tanh_scaled(float os) {
    const float e = fast_exp2(os);
#if __has_builtin(__builtin_amdgcn_rcpf)
    const float r = __builtin_amdgcn_rcpf(e + 1.0f);
#else
    const float r = 1.0f / (e + 1.0f);
#endif
    return fmaf(-2.0f, r, 1.0f);
}

__global__ __launch_bounds__(256, 4) void nsde_kernel(
    const float* __restrict__ S0p, const float* __restrict__ Kp,
    const float* __restrict__ Tp,  const float* __restrict__ rfp,
    const float* __restrict__ V0p, const float* __restrict__ rhop,
    const float* __restrict__ Z1,  const float* __restrict__ Z2r,
    const float* __restrict__ W1,  const float* __restrict__ B1,
    const float* __restrict__ W2,  const float* __restrict__ B2,
    const float* __restrict__ W3,  const float* __restrict__ B3,
    float* __restrict__ out)
{
    __shared__ float nvp[2][4][64];   // [buf][net][element] = o*2log2e (incl b3), 2 KB
    __shared__ u32x2 pkx[4][64];      // [wave][element] {pk(S,V), pk(dt*s,1)}, 2 KB

    const int tid  = threadIdx.x;
    const int wave = tid >> 6;        // wave == net
    const int lane = tid & 63;
    const int q    = lane >> 4;
    const int mA   = lane & 15;
    const float rf = rfp[0];

    const float* w1g = W1 + wave * 256;   // [4][64]
    const float* b1g = B1 + wave * 64;
    const float* w2g = W2 + wave * 4096;  // [64][64] (h, g)
    const float* b2g = B2 + wave * 64;
    const float* w3g = W3 + wave * 64;    // [64]

    // ---------------- constant fragments (register-resident) ----------------
    // L1 (K=16): A[row=mA][k=q*4+j]; q==0 holds {wS, wV, wt, b1+rf*w_rf}.
    f16x4 A1[4];
    #pragma unroll
    for (int t = 0; t < 4; ++t) {
        f16x4 a = { (_Float16)0.0f, (_Float16)0.0f, (_Float16)0.0f, (_Float16)0.0f };
        if (q == 0) {
            const int h = t * 16 + mA;
            a[0] = (_Float16)w1g[0 * 64 + h];                       // S weight
            a[1] = (_Float16)w1g[1 * 64 + h];                       // V weight
            a[2] = (_Float16)w1g[3 * 64 + h];                       // dt*j weight
            a[3] = (_Float16)fmaf(rf, w1g[2 * 64 + h], b1g[h]);     // bias (x1.0)
        }
        A1[t] = a;
    }

    // L2 (K=32): A[row -> g=gt*16+mA][slot (kt,q*8+j) -> h1=H(kt,q*8+j)]
    f16x8 A2[4][2];
    #pragma unroll
    for (int gt = 0; gt < 4; ++gt)
        #pragma unroll
        for (int kt = 0; kt < 2; ++kt) {
            f16x8 a;
            #pragma unroll
            for (int j = 0; j < 8; ++j) {
                const int h1 = (2 * kt + (j >> 2)) * 16 + 4 * q + (j & 3);
                a[j] = (_Float16)w2g[h1 * 64 + gt * 16 + mA];
            }
            A2[gt][kt] = a;
        }

    // L3 (K=32 x2): row 0 = w3 * 2log2e (same baked permutation), rest zero.
    f16x8 A3[2];
    #pragma unroll
    for (int kt = 0; kt < 2; ++kt) {
        f16x8 a;
        #pragma unroll
        for (int j = 0; j < 8; ++j) a[j] = (_Float16)0.0f;
        if (mA == 0) {
            #pragma unroll
            for (int j = 0; j < 8; ++j) {
                const int g = (2 * kt + (j >> 2)) * 16 + 4 * q + (j & 3);
                a[j] = (_Float16)(w3g[g] * KEXP);
            }
        }
        A3[kt] = a;
    }

    // L2 bias C-splats (row = 4q+r); L1 zero C; L3 C = b3*2log2e splat.
    f32x4 cinit2[4];
    #pragma unroll
    for (int t = 0; t < 4; ++t)
        #pragma unroll
        for (int r = 0; r < 4; ++r)
            cinit2[t][r] = b2g[t * 16 + 4 * q + r];
    const f32x4 zc = { 0.0f, 0.0f, 0.0f, 0.0f };
    const float b3s = B3[wave] * KEXP;
    const f32x4 cinit3 = { b3s, b3s, b3s, b3s };

    // ---------------- per-element state ----------------
    const int ebase = blockIdx.x * 64;
    const int d_own = (ebase + lane) & (D_OPT - 1);
    const float dt_own  = Tp[d_own] * (1.0f / (float)M_STEPS);
    const float sdt_own = sqrtf(dt_own);

    float Sreg = S0p[d_own];
    float Vreg = V0p[0];
    float dts  = 0.0f;                // running dt*s for NEXT packed word
    {
        u32x2 pk0;
        pk0[0] = pk2u(Sreg, Vreg);
        pk0[1] = pk2u(0.0f, 1.0f);    // {dt*j at step 0, bias multiplier}
        pkx[wave][lane] = pk0;
    }

    const float rho   = rhop[0];
    const float rho_c = sqrtf(1.0f - rho * rho);
    const size_t estep = (size_t)N_SIM * D_OPT;
    const float* z1p = Z1  + (size_t)ebase + (size_t)lane;
    const float* z2p = Z2r + (size_t)ebase + (size_t)lane;

    float z1c = *z1p;           // step 0 values
    float z2c = *z2p;
    z1p += estep; z2p += estep; // -> step 1

    #pragma unroll 1
    for (int s = 0; s < M_STEPS; ++s) {
        // prefetch next-step z (stays in flight across the lgkm-only barrier)
        const float z1n = *z1p;
        const float z2n = *z2p;
        const size_t adv = (s < M_STEPS - 2) ? estep : (size_t)0;
        z1p += adv; z2p += adv;

        #pragma unroll 2
        for (int mt = 0; mt < 4; ++mt) {
            // feature B-fragment = raw exchange word (zero VALU)
            const u32x2 pksv = pkx[wave][mt * 16 + mA];
            const f16x4 B1f = __builtin_bit_cast(f16x4, pksv);

            // L1 -> pack relu(h1) into B2 (adjacent acc pairs = baked slots)
            u32x4 b2u[2];
            #pragma unroll
            for (int t = 0; t < 4; ++t) {
                const f32x4 acc = __builtin_amdgcn_mfma_f32_16x16x16f16(
                                      A1[t], B1f, zc, 0, 0, 0);
                b2u[t >> 1][(t & 1) * 2 + 0] = pk_relu_cvt(acc[0], acc[1]);
                b2u[t >> 1][(t & 1) * 2 + 1] = pk_relu_cvt(acc[2], acc[3]);
            }
            const f16x8 B2f0 = __builtin_bit_cast(f16x8, b2u[0]);
            const f16x8 B2f1 = __builtin_bit_cast(f16x8, b2u[1]);

            // L2 -> pack relu(h2) into B3
            u32x4 b3u[2];
            #pragma unroll
            for (int gt = 0; gt < 4; ++gt) {
                f32x4 acc = __builtin_amdgcn_mfma_f32_16x16x32_f16(
                                A2[gt][0], B2f0, cinit2[gt], 0, 0, 0);
                acc = __builtin_amdgcn_mfma_f32_16x16x32_f16(
                                A2[gt][1], B2f1, acc, 0, 0, 0);
                b3u[gt >> 1][(gt & 1) * 2 + 0] = pk_relu_cvt(acc[0], acc[1]);
                b3u[gt >> 1][(gt & 1) * 2 + 1] = pk_relu_cvt(acc[2], acc[3]);
            }

            // L3: o*2log2e (+b3 splat) lands in row 0 = lanes q==0, reg 0
            f32x4 acc3 = __builtin_amdgcn_mfma_f32_16x16x32_f16(
                             A3[0], __builtin_bit_cast(f16x8, b3u[0]), cinit3, 0, 0, 0);
            acc3 = __builtin_amdgcn_mfma_f32_16x16x32_f16(
                             A3[1], __builtin_bit_cast(f16x8, b3u[1]), acc3, 0, 0, 0);

            if (q == 0)
                nvp[s & 1][wave][mt * 16 + mA] = acc3[0];
        }

        // lgkm-only barrier: drain DS writes, sync waves, leave vmcnt in flight
        __builtin_amdgcn_sched_barrier(0);
        asm volatile("s_waitcnt lgkmcnt(0)\n\ts_barrier" ::: "memory");
        __builtin_amdgcn_sched_barrier(0);

        // ---- once-per-lane SDE update of own element e == lane ----
        {
            const float N0 = tanh_scaled(nvp[s & 1][0][lane]);
            const float N1 = tanh_scaled(nvp[s & 1][1][lane]);
            const float N2 = tanh_scaled(nvp[s & 1][2][lane]);
            const float N3 = tanh_scaled(nvp[s & 1][3][lane]);
            const float z2 = fmaf(rho, z1c, rho_c * z2c);
            const float fS = fmaf(N1 * sdt_own, z1c, N0 * dt_own);
            const float fV = fmaf(N3 * sdt_own, z2, N2 * dt_own);
            Sreg = fmaf(Sreg, fS, Sreg);
            Vreg = fmaf(Vreg, fV, Vreg);
            dts += dt_own;                       // dt*(s+1)
            u32x2 pkn;
            pkn[0] = pk2u(Sreg, Vreg);
            pkn[1] = pk2u(dts, 1.0f);            // next step's {dt*j, 1}
            pkx[wave][lane] = pkn;
            z1c = z1n; z2c = z2n;
        }
    }

    // ---- payoff: wave 0, lane == element ----
    if (wave == 0) {
        const float Td  = dt_own * (float)M_STEPS;
        const float pay = fmaxf(Sreg - Kp[d_own], 0.0f);
        atomicAdd(&out[d_own], __expf(-rf * Td) * pay * (1.0f / (float)N_SIM));
    }
}

extern "C" void kernel_launch(void* const* d_in, const int* in_sizes, int n_in,
                              void* d_out, int out_size, void* d_ws, size_t ws_size,
                              hipStream_t stream)
{
    const float* S0  = (const float*)d_in[0];
    const float* K   = (const float*)d_in[1];
    const float* T   = (const float*)d_in[2];
    const float* rf  = (const float*)d_in[3];
    const float* V0  = (const float*)d_in[4];
    const float* rho = (const float*)d_in[5];
    const float* Z1  = (const float*)d_in[6];
    const float* Z2r = (const float*)d_in[7];
    const float* W1  = (const float*)d_in[8];
    const float* B1  = (const float*)d_in[9];
    const float* W2  = (const float*)d_in[10];
    const float* B2  = (const float*)d_in[11];
    const float* W3  = (const float*)d_in[12];
    const float* B3  = (const float*)d_in[13];
    float* out = (float*)d_out;

    hipMemsetAsync(out, 0, (size_t)out_size * sizeof(float), stream);

    const int total = N_SIM * D_OPT;              // 262144 elements
    const int grid  = total / 64;                 // 64 elements per block
    nsde_kernel<<<grid, 256, 0, stream>>>(S0, K, T, rf, V0, rho, Z1, Z2r,
                                          W1, B1, W2, B2, W3, B3, out);
}

// Round 11
// 703.778 us; speedup vs baseline: 1.0663x; 1.0663x over previous
//
#include <hip/hip_runtime.h>
#include <math.h>

#define D_OPT   128
#define N_SIM   2048
#define M_STEPS 64
#define HID     64

// Round 17: de-replicate the update phase.
// R16 confirmed (rocprof 716->699; MfmaUtil 64, VALU 66.5). Remaining
// replicated work: all 4 waves computed the IDENTICAL update (same elements,
// same 4 tanh chains, same S,V -> the 4 pkx planes were byte-identical) and
// issued same-address z loads. R17: one shared pkx[64]; update + z loads on
// wave 0 only; second lgkm-only barrier publishes pkx to the other waves
// (co-resident blocks fill their SIMDs meanwhile). Block VALU issue/step
// ~632 -> ~542. Everything else = R16 (validated).

typedef _Float16 f16x8 __attribute__((ext_vector_type(8)));
typedef _Float16 f16x4 __attribute__((ext_vector_type(4)));
typedef _Float16 f16x2 __attribute__((ext_vector_type(2)));
typedef float    f32x4 __attribute__((ext_vector_type(4)));
typedef unsigned int u32;
typedef u32 u32x2 __attribute__((ext_vector_type(2)));
typedef u32 u32x4 __attribute__((ext_vector_type(4)));

#define KEXP 2.8853900817779268f   // 2 * log2(e)

__device__ __forceinline__ u32 pk2u(float a, float b) {
#if __has_builtin(__builtin_amdgcn_cvt_pkrtz)
    return __builtin_bit_cast(u32, __builtin_amdgcn_cvt_pkrtz(a, b));
#else
    f16x2 p; p[0] = (_Float16)a; p[1] = (_Float16)b;
    return __builtin_bit_cast(u32, p);
#endif
}

__device__ __forceinline__ u32 pk_relu_cvt(float a, float b) {
    f16x2 p = __builtin_bit_cast(f16x2, pk2u(a, b));
    const f16x2 z = { (_Float16)0.0f, (_Float16)0.0f };
#if __has_builtin(__builtin_elementwise_max)
    p = __builtin_elementwise_max(p, z);
#else
    p[0] = p[0] > z[0] ? p[0] : z[0];
    p[1] = p[1] > z[1] ? p[1] : z[1];
#endif
    return __builtin_bit_cast(u32, p);
}

__device__ __forceinline__ float fast_exp2(float x) {
#if __has_builtin(__builtin_amdgcn_exp2f)
    return __builtin_amdgcn_exp2f(x);
#else
    return __expf(x * 0.6931471805599453f);
#endif
}

// tanh from o' = 2*log2e*o:  1 - 2*rcp(exp2(o')+1)
__device__ __forceinline__ float tanh_scaled(float os) {
    const float e = fast_exp2(os);
#if __has_builtin(__builtin_amdgcn_rcpf)
    const float r = __builtin_amdgcn_rcpf(e + 1.0f);
#else
    const float r = 1.0f / (e + 1.0f);
#endif
    return fmaf(-2.0f, r, 1.0f);
}

// lgkm-only barrier: drain DS, sync waves, leave vmcnt in flight
#define LBAR()                                                                \
  do {                                                                        \
    __builtin_amdgcn_sched_barrier(0);                                        \
    asm volatile("s_waitcnt lgkmcnt(0)\n\ts_barrier" ::: "memory");           \
    __builtin_amdgcn_sched_barrier(0);                                        \
  } while (0)

__global__ __launch_bounds__(256, 4) void nsde_kernel(
    const float* __restrict__ S0p, const float* __restrict__ Kp,
    const float* __restrict__ Tp,  const float* __restrict__ rfp,
    const float* __restrict__ V0p, const float* __restrict__ rhop,
    const float* __restrict__ Z1,  const float* __restrict__ Z2r,
    const float* __restrict__ W1,  const float* __restrict__ B1,
    const float* __restrict__ W2,  const float* __restrict__ B2,
    const float* __restrict__ W3,  const float* __restrict__ B3,
    float* __restrict__ out)
{
    __shared__ float nvp[4][64];      // [net][element] = o*2log2e (incl b3), 1 KB
    __shared__ u32x2 pkx[64];         // [element] {pk(S,V), pk(dt*s,1)} SHARED, 0.5 KB

    const int tid  = threadIdx.x;
    const int wave = tid >> 6;        // wave == net
    const int lane = tid & 63;
    const int q    = lane >> 4;
    const int mA   = lane & 15;
    const float rf = rfp[0];

    const float* w1g = W1 + wave * 256;   // [4][64]
    const float* b1g = B1 + wave * 64;
    const float* w2g = W2 + wave * 4096;  // [64][64] (h, g)
    const float* b2g = B2 + wave * 64;
    const float* w3g = W3 + wave * 64;    // [64]

    // ---------------- constant fragments (register-resident) ----------------
    // L1 (K=16): A[row=mA][k=q*4+j]; q==0 holds {wS, wV, wt, b1+rf*w_rf}.
    f16x4 A1[4];
    #pragma unroll
    for (int t = 0; t < 4; ++t) {
        f16x4 a = { (_Float16)0.0f, (_Float16)0.0f, (_Float16)0.0f, (_Float16)0.0f };
        if (q == 0) {
            const int h = t * 16 + mA;
            a[0] = (_Float16)w1g[0 * 64 + h];                       // S weight
            a[1] = (_Float16)w1g[1 * 64 + h];                       // V weight
            a[2] = (_Float16)w1g[3 * 64 + h];                       // dt*j weight
            a[3] = (_Float16)fmaf(rf, w1g[2 * 64 + h], b1g[h]);     // bias (x1.0)
        }
        A1[t] = a;
    }

    // L2 (K=32): A[row -> g=gt*16+mA][slot (kt,q*8+j) -> h1=H(kt,q*8+j)]
    f16x8 A2[4][2];
    #pragma unroll
    for (int gt = 0; gt < 4; ++gt)
        #pragma unroll
        for (int kt = 0; kt < 2; ++kt) {
            f16x8 a;
            #pragma unroll
            for (int j = 0; j < 8; ++j) {
                const int h1 = (2 * kt + (j >> 2)) * 16 + 4 * q + (j & 3);
                a[j] = (_Float16)w2g[h1 * 64 + gt * 16 + mA];
            }
            A2[gt][kt] = a;
        }

    // L3 (K=32 x2): row 0 = w3 * 2log2e (same baked permutation), rest zero.
    f16x8 A3[2];
    #pragma unroll
    for (int kt = 0; kt < 2; ++kt) {
        f16x8 a;
        #pragma unroll
        for (int j = 0; j < 8; ++j) a[j] = (_Float16)0.0f;
        if (mA == 0) {
            #pragma unroll
            for (int j = 0; j < 8; ++j) {
                const int g = (2 * kt + (j >> 2)) * 16 + 4 * q + (j & 3);
                a[j] = (_Float16)(w3g[g] * KEXP);
            }
        }
        A3[kt] = a;
    }

    // L2 bias C-splats (row = 4q+r); L1 zero C; L3 C = b3*2log2e splat.
    f32x4 cinit2[4];
    #pragma unroll
    for (int t = 0; t < 4; ++t)
        #pragma unroll
        for (int r = 0; r < 4; ++r)
            cinit2[t][r] = b2g[t * 16 + 4 * q + r];
    const f32x4 zc = { 0.0f, 0.0f, 0.0f, 0.0f };
    const float b3s = B3[wave] * KEXP;
    const f32x4 cinit3 = { b3s, b3s, b3s, b3s };

    // ---------------- per-element state (wave 0 owns the SDE state) ----------------
    const int ebase = blockIdx.x * 64;
    const int d_own = (ebase + lane) & (D_OPT - 1);
    const float dt_own  = Tp[d_own] * (1.0f / (float)M_STEPS);
    const float sdt_own = sqrtf(dt_own);

    float Sreg = S0p[d_own];
    float Vreg = V0p[0];
    float dts  = 0.0f;                // running dt*s for NEXT packed word
    if (wave == 0) {
        u32x2 pk0;
        pk0[0] = pk2u(Sreg, Vreg);
        pk0[1] = pk2u(0.0f, 1.0f);    // {dt*j at step 0, bias multiplier}
        pkx[lane] = pk0;
    }

    const float rho   = rhop[0];
    const float rho_c = sqrtf(1.0f - rho * rho);
    const size_t estep = (size_t)N_SIM * D_OPT;
    const float* z1p = Z1  + (size_t)ebase + (size_t)lane;
    const float* z2p = Z2r + (size_t)ebase + (size_t)lane;

    float z1c = 0.0f, z2c = 0.0f;
    if (wave == 0) {
        z1c = *z1p;               // step 0 values
        z2c = *z2p;
    }
    z1p += estep; z2p += estep;   // -> step 1

    __syncthreads();              // publish initial pkx

    #pragma unroll 1
    for (int s = 0; s < M_STEPS; ++s) {
        // wave-0-only prefetch of next-step z (in flight across both barriers)
        float z1n = 0.0f, z2n = 0.0f;
        if (wave == 0) {
            z1n = *z1p;
            z2n = *z2p;
        }
        const size_t adv = (s < M_STEPS - 2) ? estep : (size_t)0;
        z1p += adv; z2p += adv;

        #pragma unroll 2
        for (int mt = 0; mt < 4; ++mt) {
            // feature B-fragment = raw shared exchange word (zero VALU)
            const u32x2 pksv = pkx[mt * 16 + mA];
            const f16x4 B1f = __builtin_bit_cast(f16x4, pksv);

            // L1 -> pack relu(h1) into B2 (adjacent acc pairs = baked slots)
            u32x4 b2u[2];
            #pragma unroll
            for (int t = 0; t < 4; ++t) {
                const f32x4 acc = __builtin_amdgcn_mfma_f32_16x16x16f16(
                                      A1[t], B1f, zc, 0, 0, 0);
                b2u[t >> 1][(t & 1) * 2 + 0] = pk_relu_cvt(acc[0], acc[1]);
                b2u[t >> 1][(t & 1) * 2 + 1] = pk_relu_cvt(acc[2], acc[3]);
            }
            const f16x8 B2f0 = __builtin_bit_cast(f16x8, b2u[0]);
            const f16x8 B2f1 = __builtin_bit_cast(f16x8, b2u[1]);

            // L2 -> pack relu(h2) into B3
            u32x4 b3u[2];
            #pragma unroll
            for (int gt = 0; gt < 4; ++gt) {
                f32x4 acc = __builtin_amdgcn_mfma_f32_16x16x32_f16(
                                A2[gt][0], B2f0, cinit2[gt], 0, 0, 0);
                acc = __builtin_amdgcn_mfma_f32_16x16x32_f16(
                                A2[gt][1], B2f1, acc, 0, 0, 0);
                b3u[gt >> 1][(gt & 1) * 2 + 0] = pk_relu_cvt(acc[0], acc[1]);
                b3u[gt >> 1][(gt & 1) * 2 + 1] = pk_relu_cvt(acc[2], acc[3]);
            }

            // L3: o*2log2e (+b3 splat) lands in row 0 = lanes q==0, reg 0
            f32x4 acc3 = __builtin_amdgcn_mfma_f32_16x16x32_f16(
                             A3[0], __builtin_bit_cast(f16x8, b3u[0]), cinit3, 0, 0, 0);
            acc3 = __builtin_amdgcn_mfma_f32_16x16x32_f16(
                             A3[1], __builtin_bit_cast(f16x8, b3u[1]), acc3, 0, 0, 0);

            if (q == 0)
                nvp[wave][mt * 16 + mA] = acc3[0];
        }

        LBAR();   // publish nvp to wave 0

        // ---- SDE update on wave 0 only (pkx content was identical per wave) ----
        if (wave == 0) {
            const float N0 = tanh_scaled(nvp[0][lane]);
            const float N1 = tanh_scaled(nvp[1][lane]);
            const float N2 = tanh_scaled(nvp[2][lane]);
            const float N3 = tanh_scaled(nvp[3][lane]);
            const float z2 = fmaf(rho, z1c, rho_c * z2c);
            const float fS = fmaf(N1 * sdt_own, z1c, N0 * dt_own);
            const float fV = fmaf(N3 * sdt_own, z2, N2 * dt_own);
            Sreg = fmaf(Sreg, fS, Sreg);
            Vreg = fmaf(Vreg, fV, Vreg);
            dts += dt_own;                       // dt*(s+1)
            u32x2 pkn;
            pkn[0] = pk2u(Sreg, Vreg);
            pkn[1] = pk2u(dts, 1.0f);            // next step's {dt*j, 1}
            pkx[lane] = pkn;
            z1c = z1n; z2c = z2n;
        }

        LBAR();   // publish pkx to all waves
    }

    // ---- payoff: wave 0, lane == element ----
    if (wave == 0) {
        const float Td  = dt_own * (float)M_STEPS;
        const float pay = fmaxf(Sreg - Kp[d_own], 0.0f);
        atomicAdd(&out[d_own], __expf(-rf * Td) * pay * (1.0f / (float)N_SIM));
    }
}

extern "C" void kernel_launch(void* const* d_in, const int* in_sizes, int n_in,
                              void* d_out, int out_size, void* d_ws, size_t ws_size,
                              hipStream_t stream)
{
    const float* S0  = (const float*)d_in[0];
    const float* K   = (const float*)d_in[1];
    const float* T   = (const float*)d_in[2];
    const float* rf  = (const float*)d_in[3];
    const float* V0  = (const float*)d_in[4];
    const float* rho = (const float*)d_in[5];
    const float* Z1  = (const float*)d_in[6];
    const float* Z2r = (const float*)d_in[7];
    const float* W1  = (const float*)d_in[8];
    const float* B1  = (const float*)d_in[9];
    const float* W2  = (const float*)d_in[10];
    const float* B2  = (const float*)d_in[11];
    const float* W3  = (const float*)d_in[12];
    const float* B3  = (const float*)d_in[13];
    float* out = (float*)d_out;

    hipMemsetAsync(out, 0, (size_t)out_size * sizeof(float), stream);

    const int total = N_SIM * D_OPT;              // 262144 elements
    const int grid  = total / 64;                 // 64 elements per block
    nsde_kernel<<<grid, 256, 0, stream>>>(S0, K, T, rf, V0, rho, Z1, Z2r,
                                          W1, B1, W2, B2, W3, B3, out);
}